// Round 7
// baseline (252.588 us; speedup 1.0000x reference)
//
#include <hip/hip_runtime.h>

typedef __bf16 bf16x8 __attribute__((ext_vector_type(8)));
typedef __bf16 bf16x4 __attribute__((ext_vector_type(4)));
typedef float  f32x4  __attribute__((ext_vector_type(4)));

#define B_    4
#define S_    2048
#define E_    1024
#define H_    16
#define D_    64
#define MROWS (B_*S_)   // 8192
#define HD3   3072

// log2(e) / sqrt(D) — folded into Q in the GEMM epilogue
#define SCORE_SCALE 0.18033688011112043f

__device__ __forceinline__ void load_lds16(const void* g, void* l) {
  __builtin_amdgcn_global_load_lds((__attribute__((address_space(1))) void*)g,
                                   (__attribute__((address_space(3))) void*)l,
                                   16, 0, 0);
}

__device__ __forceinline__ f32x4 mfma16(bf16x8 a, bf16x8 b, f32x4 c) {
  return __builtin_amdgcn_mfma_f32_16x16x32_bf16(a, b, c, 0, 0, 0);
}

// swizzled LDS element offset, 64-col bf16 rows: data chunk (8 elems) lands at
// physical chunk (dchunk ^ (row&7))  -> all fragment reads are <=2-way (free)
__device__ __forceinline__ int swz(int row, int dchunk) {
  return row * 64 + ((dchunk ^ (row & 7)) * 8);
}

// ---------------- fused prep: cvt_x | pack_w | pack_wo ----------------

__global__ void prep(const float4* __restrict__ x, const float* __restrict__ Wq,
                     const float* __restrict__ Wk, const float* __restrict__ Wv,
                     const float* __restrict__ bq, const float* __restrict__ bk,
                     const float* __restrict__ bv, const float* __restrict__ Wo,
                     __bf16* __restrict__ xb, __bf16* __restrict__ Wt,
                     float* __restrict__ bqkv, __bf16* __restrict__ Wot) {
  __shared__ float t[64][65];
  int bid = blockIdx.x;
  if (bid < 8192) {                      // cvt_x: fp32 x -> bf16
    int id = bid * 256 + threadIdx.x;
    float4 v = x[id];
    bf16x4 o = { (__bf16)v.x, (__bf16)v.y, (__bf16)v.z, (__bf16)v.w };
    *(bf16x4*)(xb + 4 * (size_t)id) = o;
    return;
  }
  int tx = threadIdx.x & 63;
  int ty = threadIdx.x >> 6;
  if (bid < 8960) {                      // pack_w: [H,E,D] -> Wt[3*H*D][E]
    int b2 = bid - 8192;                 // 768
    int e0 = (b2 & 15) * 64;
    int h  = (b2 >> 4) & 15;
    int p  = b2 >> 8;
    const float* W    = (p == 0) ? Wq : (p == 1) ? Wk : Wv;
    const float* bsrc = (p == 0) ? bq : (p == 1) ? bk : bv;
#pragma unroll
    for (int r = 0; r < 16; ++r) {
      int eL = ty + r * 4;
      t[eL][tx] = W[((size_t)h * 1024 + (e0 + eL)) * 64 + tx];
    }
    __syncthreads();
#pragma unroll
    for (int r = 0; r < 16; ++r) {
      int d = ty + r * 4;
      Wt[((size_t)(p * 1024 + h * 64 + d)) * 1024 + e0 + tx] = (__bf16)t[tx][d];
    }
    if ((b2 & 15) == 0 && threadIdx.x < 64)
      bqkv[p * 1024 + h * 64 + threadIdx.x] = bsrc[h * 64 + threadIdx.x];
  } else {                               // pack_wo: Wo[1024,1024] -> Wot[e][hd]
    int b2 = bid - 8960;                 // 256
    int hd0 = (b2 >> 4) * 64;
    int e0  = (b2 & 15) * 64;
#pragma unroll
    for (int r = 0; r < 16; ++r) {
      int hdL = ty + r * 4;
      t[hdL][tx] = Wo[(size_t)(hd0 + hdL) * 1024 + e0 + tx];
    }
    __syncthreads();
#pragma unroll
    for (int r = 0; r < 16; ++r) {
      int eL = ty + r * 4;
      Wot[(size_t)(e0 + eL) * 1024 + hd0 + tx] = (__bf16)t[tx][eL];
    }
  }
}

// ---------------- GEMM: C[M,N] = A[M,K] @ Bt[N,K]^T + bias[N] ----------------
// 128x128 tile, BK=64, XOR-swizzled single LDS buffer, overlapped staging.
// MODE 0: C fp32. MODE 1: QKV split — cols<2048 -> QKb (Q scaled), >=2048 -> VT.

template <int MODE>
__global__ __launch_bounds__(256) void gemm_bt(const __bf16* __restrict__ A,
                                               const __bf16* __restrict__ Bt,
                                               const float* __restrict__ bias,
                                               void* __restrict__ Cout,
                                               __bf16* __restrict__ VT,
                                               int M, int N, int K) {
  __shared__ __attribute__((aligned(16))) __bf16 As[128 * 64];
  __shared__ __attribute__((aligned(16))) __bf16 Bs[128 * 64];
  int tid = threadIdx.x, wave = tid >> 6, lane = tid & 63;
  int quad = lane >> 4, cc = lane & 15;
  int nb = N >> 7;
  int bm = (int)blockIdx.x / nb, bn = (int)blockIdx.x % nb;
  const __bf16* Abase = A + (size_t)bm * 128 * K;
  const __bf16* Bbase = Bt + (size_t)bn * 128 * K;
  int wr = (wave >> 1) * 64, wc = (wave & 1) * 64;
  f32x4 acc[4][4];
#pragma unroll
  for (int i = 0; i < 4; ++i)
#pragma unroll
    for (int j = 0; j < 4; ++j) acc[i][j] = (f32x4){0.f, 0.f, 0.f, 0.f};

  int srow[4], scol[4];
#pragma unroll
  for (int p = 0; p < 4; ++p) {
    int g = tid + p * 256;               // 0..1023
    srow[p] = g >> 3;
    scol[p] = ((g & 7) ^ (srow[p] & 7)) * 8;
  }
#pragma unroll
  for (int p = 0; p < 4; ++p) {
    load_lds16(Abase + (size_t)srow[p] * K + scol[p], &As[(tid + p * 256) * 8]);
    load_lds16(Bbase + (size_t)srow[p] * K + scol[p], &Bs[(tid + p * 256) * 8]);
  }

  for (int k0 = 0; k0 < K; k0 += 64) {
    __syncthreads();                     // staging for k0 visible
    bf16x8 af[2][4], bf[2][4];
#pragma unroll
    for (int kk = 0; kk < 2; ++kk) {
#pragma unroll
      for (int i = 0; i < 4; ++i) af[kk][i] = *(const bf16x8*)&As[swz(wr + i * 16 + cc, kk * 4 + quad)];
#pragma unroll
      for (int j = 0; j < 4; ++j) bf[kk][j] = *(const bf16x8*)&Bs[swz(wc + j * 16 + cc, kk * 4 + quad)];
    }
    __syncthreads();                     // all waves done reading LDS
    if (k0 + 64 < K) {                   // stage k0+64 — overlaps the MFMAs below
      int kn = k0 + 64;
#pragma unroll
      for (int p = 0; p < 4; ++p) {
        load_lds16(Abase + (size_t)srow[p] * K + kn + scol[p], &As[(tid + p * 256) * 8]);
        load_lds16(Bbase + (size_t)srow[p] * K + kn + scol[p], &Bs[(tid + p * 256) * 8]);
      }
    }
#pragma unroll
    for (int kk = 0; kk < 2; ++kk)
#pragma unroll
      for (int i = 0; i < 4; ++i)
#pragma unroll
        for (int j = 0; j < 4; ++j) acc[i][j] = mfma16(af[kk][i], bf[kk][j], acc[i][j]);
  }

#pragma unroll
  for (int j = 0; j < 4; ++j) {
    int col = bn * 128 + wc + j * 16 + cc;
    float bv = bias[col];
#pragma unroll
    for (int i = 0; i < 4; ++i) {
      int row0 = bm * 128 + wr + i * 16 + quad * 4;
      if (MODE == 0) {
#pragma unroll
        for (int r = 0; r < 4; ++r)
          ((float*)Cout)[(size_t)(row0 + r) * N + col] = acc[i][j][r] + bv;
      } else if (col < 2048) {           // Q|K -> QKb (stride 2048), Q scaled
        float sc = (col < 1024) ? SCORE_SCALE : 1.0f;
#pragma unroll
        for (int r = 0; r < 4; ++r)
          ((__bf16*)Cout)[(size_t)(row0 + r) * 2048 + col] = (__bf16)((acc[i][j][r] + bv) * sc);
      } else {                           // V -> VT[(b*16+h)*64+d][s], packed x4
        int bh = (row0 >> 11) * 16 + ((col >> 6) & 15);
        int d  = col & 63;
        bf16x4 pk;
#pragma unroll
        for (int r = 0; r < 4; ++r) pk[r] = (__bf16)(acc[i][j][r] + bv);
        *(bf16x4*)&VT[((size_t)(bh * 64 + d)) * 2048 + (row0 & 2047)] = pk;
      }
    }
  }
}

// ---------------- causal flash attention ------------------------------------
// Q-tile 256, 512 threads (8 waves x 32 q-rows), KV 64 double-buffered.
// S^T trick -> P store is one ds_write_b64 per (i,j). Ps overlays Qs.
// No-max softmax (additive) => kv-parity split of the longest q-tiles (7,6)
// into 2 blocks each; fp32 partials merged by the merge kernel.
// Grid 640, longest-first: g=bx>>6: 24,20,16,16,16,14,14,12,8,4 tiles.

__global__ __launch_bounds__(512, 4) void attn(const __bf16* __restrict__ QKb,
                                               const __bf16* __restrict__ VT,
                                               __bf16* __restrict__ O,
                                               float* __restrict__ PartO,
                                               float* __restrict__ PartL) {
  int bx = blockIdx.x;
  int bh = bx & 63;
  int g  = bx >> 6;                  // 0..9 schedule slot
  int qt, par = 0, split = 0;
  switch (g) {
    case 0: qt = 5; break;
    case 1: qt = 4; break;
    case 2: qt = 7; split = 1; break;
    case 3: qt = 7; par = 1; split = 1; break;
    case 4: qt = 3; break;
    case 5: qt = 6; split = 1; break;
    case 6: qt = 6; par = 1; split = 1; break;
    case 7: qt = 2; break;
    case 8: qt = 1; break;
    default: qt = 0; break;
  }
  int h  = bh & 15;
  int b  = bh >> 4;
  int q0 = qt * 256;
  int tid = threadIdx.x, wave = tid >> 6, lane = tid & 63;
  int quad = lane >> 4, c = lane & 15;
  int tstep = split ? 2 : 1;

  // 64 KB: Qs 32K (reused as per-wave Ps) | Ks 2x8K | Vs 2x8K
  __shared__ __attribute__((aligned(16))) __bf16 smem[32768];
  __bf16* Qs = smem;                         // 256*64
  __bf16* Ks = smem + 16384;                 // 2 * 64*64
  __bf16* Vs = smem + 24576;                 // 2 * 64*64 (V^T tiles [d][kv])
  __bf16* Ps = smem + wave * 2048;           // own wave's Q rows (dead after prologue)

  // hoisted per-thread staging addresses (advance additively per tile)
  int srow = tid >> 3, sx = ((tid & 7) ^ (srow & 7)) * 8;
  const __bf16* Kp = QKb + ((size_t)(b * S_ + par * 64 + srow)) * 2048 + 1024 + h * 64 + sx;
  const __bf16* Vp = VT + (size_t)bh * (64 * 2048) + (size_t)srow * 2048 + par * 64 + sx;
  const int kstep = tstep * 64 * 2048;
  const int vstep = tstep * 64;
  int ldst = tid * 8;                        // LDS staging dst (elems)

  const __bf16* Qbase = QKb + (size_t)(b * S_ + q0) * 2048 + h * 64;
#pragma unroll
  for (int p = 0; p < 4; ++p) {
    int gg = tid + p * 512;           // 0..2047
    int row = gg >> 3, pch = gg & 7;
    load_lds16(Qbase + (size_t)row * 2048 + (pch ^ (row & 7)) * 8, &Qs[gg * 8]);
  }
  load_lds16(Kp, &Ks[ldst]);          // stage KV tile t=par into buf 0
  load_lds16(Vp, &Vs[ldst]);
  Kp += kstep; Vp += vstep;
  __syncthreads();

  bf16x8 qf[2][2];
#pragma unroll
  for (int i = 0; i < 2; ++i)
#pragma unroll
    for (int kk = 0; kk < 2; ++kk)
      qf[i][kk] = *(const bf16x8*)&Qs[swz(wave * 32 + i * 16 + c, kk * 4 + quad)];

  // hoisted fragment offsets (same formula serves kf, vf, pf)
  int offA[4][2], offW[2][4];
#pragma unroll
  for (int j = 0; j < 4; ++j)
#pragma unroll
    for (int kk = 0; kk < 2; ++kk) offA[j][kk] = swz(j * 16 + c, kk * 4 + quad);
#pragma unroll
  for (int i = 0; i < 2; ++i) {
    int q_l = i * 16 + c;
#pragma unroll
    for (int j = 0; j < 4; ++j) {
      int dch8 = j * 2 + (quad >> 1);
      offW[i][j] = q_l * 64 + ((dch8 ^ (q_l & 7)) * 8) + (quad & 1) * 4;
    }
  }

  const __bf16 one_b = (__bf16)1.0f;
  bf16x8 ones = { one_b, one_b, one_b, one_b, one_b, one_b, one_b, one_b };

  f32x4 acc_o[2][4], acc_l[2];
#pragma unroll
  for (int i = 0; i < 2; ++i) {
    acc_l[i] = (f32x4){0.f, 0.f, 0.f, 0.f};
#pragma unroll
    for (int j = 0; j < 4; ++j) acc_o[i][j] = (f32x4){0.f, 0.f, 0.f, 0.f};
  }

  int qwave = q0 + wave * 32;         // this wave's first q row
  int ntiles = qt * 4 + 4;
  int cur = 0;
  for (int t = par; t < ntiles; t += tstep) {
    if (t + tstep < ntiles) {         // prefetch next KV tile (other buffer)
      load_lds16(Kp, &Ks[(cur ^ 1) * 4096 + ldst]);
      load_lds16(Vp, &Vs[(cur ^ 1) * 4096 + ldst]);
      Kp += kstep; Vp += vstep;
    }

    int kv0 = t * 64;
    if (kv0 <= qwave + 31) {          // wave has at least one unmasked row
      const __bf16* Kc = Ks + cur * 4096;
      const __bf16* Vc = Vs + cur * 4096;

      // S^T = K Q^T : rows=kv, cols=q  (log2-domain scores, Q pre-scaled)
      f32x4 acc_t[2][4];
#pragma unroll
      for (int i = 0; i < 2; ++i)
#pragma unroll
        for (int j = 0; j < 4; ++j) acc_t[i][j] = (f32x4){0.f, 0.f, 0.f, 0.f};
      bf16x8 kf[4][2];
#pragma unroll
      for (int j = 0; j < 4; ++j)
#pragma unroll
        for (int kk = 0; kk < 2; ++kk)
          kf[j][kk] = *(const bf16x8*)&Kc[offA[j][kk]];
#pragma unroll
      for (int i = 0; i < 2; ++i)
#pragma unroll
        for (int j = 0; j < 4; ++j)
#pragma unroll
          for (int kk = 0; kk < 2; ++kk)
            acc_t[i][j] = mfma16(kf[j][kk], qf[i][kk], acc_t[i][j]);

      // p = exp2(s); mask only when this wave straddles the diagonal
      bool domask = (kv0 + 63 > qwave);
#pragma unroll
      for (int i = 0; i < 2; ++i) {
        int q_g = qwave + i * 16 + c;              // global q row
#pragma unroll
        for (int j = 0; j < 4; ++j) {
          bf16x4 pk;
#pragma unroll
          for (int r = 0; r < 4; ++r) {
            float p = __builtin_amdgcn_exp2f(acc_t[i][j][r]);
            if (domask) {
              int kv = kv0 + j * 16 + quad * 4 + r;
              p = (kv > q_g) ? 0.f : p;
            }
            pk[r] = (__bf16)p;
          }
          *(bf16x4*)&Ps[offW[i][j]] = pk;
        }
      }

      // PV + row-sum (ones-MFMA); same-wave LDS ops are in-order
      bf16x8 pf[2][2], vf[4][2];
#pragma unroll
      for (int i = 0; i < 2; ++i)
#pragma unroll
        for (int kk = 0; kk < 2; ++kk)
          pf[i][kk] = *(const bf16x8*)&Ps[offA[i][kk]];
#pragma unroll
      for (int j = 0; j < 4; ++j)
#pragma unroll
        for (int kk = 0; kk < 2; ++kk)
          vf[j][kk] = *(const bf16x8*)&Vc[offA[j][kk]];
#pragma unroll
      for (int i = 0; i < 2; ++i) {
#pragma unroll
        for (int j = 0; j < 4; ++j)
#pragma unroll
          for (int kk = 0; kk < 2; ++kk)
            acc_o[i][j] = mfma16(pf[i][kk], vf[j][kk], acc_o[i][j]);
        acc_l[i] = mfma16(pf[i][0], ones, acc_l[i]);
        acc_l[i] = mfma16(pf[i][1], ones, acc_l[i]);
      }
    }

    __syncthreads();   // staging for t+tstep complete; buf (cur) free
    cur ^= 1;
  }

  if (!split) {
    __bf16* Obase = O + (size_t)(b * S_ + q0) * 1024 + h * 64;
#pragma unroll
    for (int i = 0; i < 2; ++i)
#pragma unroll
      for (int r = 0; r < 4; ++r) {
        float rl = 1.0f / acc_l[i][r];
        int row = wave * 32 + i * 16 + quad * 4 + r;
#pragma unroll
        for (int j = 0; j < 4; ++j)
          Obase[(size_t)row * 1024 + j * 16 + c] = (__bf16)(acc_o[i][j][r] * rl);
      }
  } else {
    int slot = par * 128 + (7 - qt) * 64 + bh;        // [0,256)
    float* PO = PartO + (size_t)slot * (256 * 64);
    float* PL = PartL + (size_t)slot * 256;
#pragma unroll
    for (int i = 0; i < 2; ++i)
#pragma unroll
      for (int r = 0; r < 4; ++r) {
        int row = wave * 32 + i * 16 + quad * 4 + r;
        if (c == 0) PL[row] = acc_l[i][r];
#pragma unroll
        for (int j = 0; j < 4; ++j)
          PO[row * 64 + j * 16 + c] = acc_o[i][j][r];
      }
  }
}

// merge the kv-parity partials for split q-tiles (qt 7,6): O = (A0+A1)/(l0+l1)
__global__ void merge(const float* __restrict__ PartO, const float* __restrict__ PartL,
                      __bf16* __restrict__ O) {
  int u  = blockIdx.x >> 2;            // 0..127: qtile (qt7: 0..63, qt6: 64..127)
  int r0 = (blockIdx.x & 3) * 64;      // row group within the 256-row q-tile
  int qt = 7 - (u >> 6);
  int bh = u & 63;
  int b = bh >> 4, h = bh & 15;
  int q0 = qt * 256;
  int tid = threadIdx.x;
  const float* A0 = PartO + (size_t)u * (256 * 64) + r0 * 64;
  const float* A1 = PartO + (size_t)(128 + u) * (256 * 64) + r0 * 64;
  const float* L0 = PartL + (size_t)u * 256 + r0;
  const float* L1 = PartL + (size_t)(128 + u) * 256 + r0;
#pragma unroll
  for (int it = 0; it < 4; ++it) {
    int e = it * 1024 + tid * 4;       // elem in 64 rows x 64 d
    int row = e >> 6, d = e & 63;
    f32x4 a0 = *(const f32x4*)&A0[e];
    f32x4 a1 = *(const f32x4*)&A1[e];
    float rl = 1.0f / (L0[row] + L1[row]);
    bf16x4 o;
#pragma unroll
    for (int k = 0; k < 4; ++k) o[k] = (__bf16)((a0[k] + a1[k]) * rl);
    *(bf16x4*)&O[(size_t)(b * S_ + q0 + r0 + row) * 1024 + h * 64 + d] = o;
  }
}

// ---------------- launcher ----------------

extern "C" void kernel_launch(void* const* d_in, const int* in_sizes, int n_in,
                              void* d_out, int out_size, void* d_ws, size_t ws_size,
                              hipStream_t stream) {
  (void)in_sizes; (void)n_in; (void)out_size; (void)ws_size;
  const float* x  = (const float*)d_in[0];
  const float* Wq = (const float*)d_in[1];
  const float* bq = (const float*)d_in[2];
  const float* Wk = (const float*)d_in[3];
  const float* bk = (const float*)d_in[4];
  const float* Wv = (const float*)d_in[5];
  const float* bv = (const float*)d_in[6];
  const float* Wo = (const float*)d_in[7];
  const float* bo = (const float*)d_in[8];

  char* w = (char*)d_ws;
  __bf16* xb   = (__bf16*)(w);                         // 16 MB (dead after gemm1)
  __bf16* Wt   = (__bf16*)(w + (16ull << 20));         //  6 MB (dead after gemm1)
  __bf16* Wot  = (__bf16*)(w + (22ull << 20));         //  2 MB
  float*  bqkv = (float*) (w + (24ull << 20));         // 12 KB
  __bf16* QKb  = (__bf16*)(w + (25ull << 20));         // 32 MB (Q|K, stride 2048)
  __bf16* Ob   = (__bf16*)(w + (57ull << 20));         // 16 MB
  __bf16* VT   = (__bf16*)(w + (73ull << 20));         // 16 MB (total 89 MB)
  // attn partials overlay the dead xb/Wt region (attn runs after gemm1)
  float* PartO = (float*)(w);                          // 16 MB (0..16)
  float* PartL = (float*)(w + (18ull << 20));          // 256 KB (18..18.25)

  prep   <<<9216, 256, 0, stream>>>((const float4*)x, Wq, Wk, Wv, bq, bk, bv, Wo,
                                    xb, Wt, bqkv, Wot);
  gemm_bt<1><<<dim3((MROWS / 128) * (3072 / 128)), 256, 0, stream>>>(xb, Wt, bqkv, (void*)QKb, VT, MROWS, 3072, 1024);
  attn   <<<640, 512, 0, stream>>>(QKb, VT, Ob, PartO, PartL);
  merge  <<<512, 256, 0, stream>>>(PartO, PartL, Ob);
  gemm_bt<0><<<dim3((MROWS / 128) * (1024 / 128)), 256, 0, stream>>>(Ob, Wot, bo, d_out, nullptr, MROWS, 1024, 1024);
}

// Round 8
// 249.286 us; speedup vs baseline: 1.0132x; 1.0132x over previous
//
#include <hip/hip_runtime.h>

typedef __bf16 bf16x8 __attribute__((ext_vector_type(8)));
typedef __bf16 bf16x4 __attribute__((ext_vector_type(4)));
typedef float  f32x4  __attribute__((ext_vector_type(4)));

#define B_    4
#define S_    2048
#define E_    1024
#define H_    16
#define D_    64
#define MROWS (B_*S_)   // 8192
#define HD3   3072

// log2(e) / sqrt(D) — folded into Q in the GEMM epilogue
#define SCORE_SCALE 0.18033688011112043f

__device__ __forceinline__ void load_lds16(const void* g, void* l) {
  __builtin_amdgcn_global_load_lds((__attribute__((address_space(1))) void*)g,
                                   (__attribute__((address_space(3))) void*)l,
                                   16, 0, 0);
}

__device__ __forceinline__ f32x4 mfma16(bf16x8 a, bf16x8 b, f32x4 c) {
  return __builtin_amdgcn_mfma_f32_16x16x32_bf16(a, b, c, 0, 0, 0);
}

// swizzled LDS element offset, 64-col bf16 rows: data chunk (8 elems) lands at
// physical chunk (dchunk ^ (row&7))  -> all fragment reads are <=2-way (free)
__device__ __forceinline__ int swz(int row, int dchunk) {
  return row * 64 + ((dchunk ^ (row & 7)) * 8);
}

// ---------------- fused prep: cvt_x | pack_w | pack_wo ----------------

__global__ void prep(const float4* __restrict__ x, const float* __restrict__ Wq,
                     const float* __restrict__ Wk, const float* __restrict__ Wv,
                     const float* __restrict__ bq, const float* __restrict__ bk,
                     const float* __restrict__ bv, const float* __restrict__ Wo,
                     __bf16* __restrict__ xb, __bf16* __restrict__ Wt,
                     float* __restrict__ bqkv, __bf16* __restrict__ Wot) {
  __shared__ float t[64][65];
  int bid = blockIdx.x;
  if (bid < 8192) {                      // cvt_x: fp32 x -> bf16
    int id = bid * 256 + threadIdx.x;
    float4 v = x[id];
    bf16x4 o = { (__bf16)v.x, (__bf16)v.y, (__bf16)v.z, (__bf16)v.w };
    *(bf16x4*)(xb + 4 * (size_t)id) = o;
    return;
  }
  int tx = threadIdx.x & 63;
  int ty = threadIdx.x >> 6;
  if (bid < 8960) {                      // pack_w: [H,E,D] -> Wt[3*H*D][E]
    int b2 = bid - 8192;                 // 768
    int e0 = (b2 & 15) * 64;
    int h  = (b2 >> 4) & 15;
    int p  = b2 >> 8;
    const float* W    = (p == 0) ? Wq : (p == 1) ? Wk : Wv;
    const float* bsrc = (p == 0) ? bq : (p == 1) ? bk : bv;
#pragma unroll
    for (int r = 0; r < 16; ++r) {
      int eL = ty + r * 4;
      t[eL][tx] = W[((size_t)h * 1024 + (e0 + eL)) * 64 + tx];
    }
    __syncthreads();
#pragma unroll
    for (int r = 0; r < 16; ++r) {
      int d = ty + r * 4;
      Wt[((size_t)(p * 1024 + h * 64 + d)) * 1024 + e0 + tx] = (__bf16)t[tx][d];
    }
    if ((b2 & 15) == 0 && threadIdx.x < 64)
      bqkv[p * 1024 + h * 64 + threadIdx.x] = bsrc[h * 64 + threadIdx.x];
  } else {                               // pack_wo: Wo[1024,1024] -> Wot[e][hd]
    int b2 = bid - 8960;                 // 256
    int hd0 = (b2 >> 4) * 64;
    int e0  = (b2 & 15) * 64;
#pragma unroll
    for (int r = 0; r < 16; ++r) {
      int hdL = ty + r * 4;
      t[hdL][tx] = Wo[(size_t)(hd0 + hdL) * 1024 + e0 + tx];
    }
    __syncthreads();
#pragma unroll
    for (int r = 0; r < 16; ++r) {
      int eL = ty + r * 4;
      Wot[(size_t)(e0 + eL) * 1024 + hd0 + tx] = (__bf16)t[tx][eL];
    }
  }
}

// ---------------- GEMM: C[M,N] = A[M,K] @ Bt[N,K]^T + bias[N] ----------------
// 128x128 tile, BK=64, XOR-swizzled single LDS buffer, overlapped staging.
// MODE 0: C fp32. MODE 1: QKV split — cols<2048 -> QKb (Q scaled), >=2048 -> VT.

template <int MODE>
__global__ __launch_bounds__(256) void gemm_bt(const __bf16* __restrict__ A,
                                               const __bf16* __restrict__ Bt,
                                               const float* __restrict__ bias,
                                               void* __restrict__ Cout,
                                               __bf16* __restrict__ VT,
                                               int M, int N, int K) {
  __shared__ __attribute__((aligned(16))) __bf16 As[128 * 64];
  __shared__ __attribute__((aligned(16))) __bf16 Bs[128 * 64];
  int tid = threadIdx.x, wave = tid >> 6, lane = tid & 63;
  int quad = lane >> 4, cc = lane & 15;
  int nb = N >> 7;
  int bm = (int)blockIdx.x / nb, bn = (int)blockIdx.x % nb;
  const __bf16* Abase = A + (size_t)bm * 128 * K;
  const __bf16* Bbase = Bt + (size_t)bn * 128 * K;
  int wr = (wave >> 1) * 64, wc = (wave & 1) * 64;
  f32x4 acc[4][4];
#pragma unroll
  for (int i = 0; i < 4; ++i)
#pragma unroll
    for (int j = 0; j < 4; ++j) acc[i][j] = (f32x4){0.f, 0.f, 0.f, 0.f};

  int srow[4], scol[4];
#pragma unroll
  for (int p = 0; p < 4; ++p) {
    int g = tid + p * 256;               // 0..1023
    srow[p] = g >> 3;
    scol[p] = ((g & 7) ^ (srow[p] & 7)) * 8;
  }
#pragma unroll
  for (int p = 0; p < 4; ++p) {
    load_lds16(Abase + (size_t)srow[p] * K + scol[p], &As[(tid + p * 256) * 8]);
    load_lds16(Bbase + (size_t)srow[p] * K + scol[p], &Bs[(tid + p * 256) * 8]);
  }

  for (int k0 = 0; k0 < K; k0 += 64) {
    __syncthreads();                     // staging for k0 visible
    bf16x8 af[2][4], bf[2][4];
#pragma unroll
    for (int kk = 0; kk < 2; ++kk) {
#pragma unroll
      for (int i = 0; i < 4; ++i) af[kk][i] = *(const bf16x8*)&As[swz(wr + i * 16 + cc, kk * 4 + quad)];
#pragma unroll
      for (int j = 0; j < 4; ++j) bf[kk][j] = *(const bf16x8*)&Bs[swz(wc + j * 16 + cc, kk * 4 + quad)];
    }
    __syncthreads();                     // all waves done reading LDS
    if (k0 + 64 < K) {                   // stage k0+64 — overlaps the MFMAs below
      int kn = k0 + 64;
#pragma unroll
      for (int p = 0; p < 4; ++p) {
        load_lds16(Abase + (size_t)srow[p] * K + kn + scol[p], &As[(tid + p * 256) * 8]);
        load_lds16(Bbase + (size_t)srow[p] * K + kn + scol[p], &Bs[(tid + p * 256) * 8]);
      }
    }
#pragma unroll
    for (int kk = 0; kk < 2; ++kk)
#pragma unroll
      for (int i = 0; i < 4; ++i)
#pragma unroll
        for (int j = 0; j < 4; ++j) acc[i][j] = mfma16(af[kk][i], bf[kk][j], acc[i][j]);
  }

#pragma unroll
  for (int j = 0; j < 4; ++j) {
    int col = bn * 128 + wc + j * 16 + cc;
    float bv = bias[col];
#pragma unroll
    for (int i = 0; i < 4; ++i) {
      int row0 = bm * 128 + wr + i * 16 + quad * 4;
      if (MODE == 0) {
#pragma unroll
        for (int r = 0; r < 4; ++r)
          ((float*)Cout)[(size_t)(row0 + r) * N + col] = acc[i][j][r] + bv;
      } else if (col < 2048) {           // Q|K -> QKb (stride 2048), Q scaled
        float sc = (col < 1024) ? SCORE_SCALE : 1.0f;
#pragma unroll
        for (int r = 0; r < 4; ++r)
          ((__bf16*)Cout)[(size_t)(row0 + r) * 2048 + col] = (__bf16)((acc[i][j][r] + bv) * sc);
      } else {                           // V -> VT[(b*16+h)*64+d][s], packed x4
        int bh = (row0 >> 11) * 16 + ((col >> 6) & 15);
        int d  = col & 63;
        bf16x4 pk;
#pragma unroll
        for (int r = 0; r < 4; ++r) pk[r] = (__bf16)(acc[i][j][r] + bv);
        *(bf16x4*)&VT[((size_t)(bh * 64 + d)) * 2048 + (row0 & 2047)] = pk;
      }
    }
  }
}

// ---------------- causal flash attention ------------------------------------
// Q-tile 256, 256 threads = 4 waves x 64 q-rows (raises MFMA per LDS byte:
// K/V fragment reads are per-wave duplicated, so fewer/fatter waves cut LDS
// traffic 208->144 KB per block-tile). KV 64 dbuf; S^T trick; Ps overlays Qs
// (per-wave 8KB = own 64 Q rows). No-max softmax; kv-parity split of qt 7,6
// with fp32 partials + merge. Grid 640, longest-first schedule.

__global__ __launch_bounds__(256, 2) void attn(const __bf16* __restrict__ QKb,
                                               const __bf16* __restrict__ VT,
                                               __bf16* __restrict__ O,
                                               float* __restrict__ PartO,
                                               float* __restrict__ PartL) {
  int bx = blockIdx.x;
  int bh = bx & 63;
  int g  = bx >> 6;                  // 0..9 schedule slot
  int qt, par = 0, split = 0;
  switch (g) {
    case 0: qt = 5; break;
    case 1: qt = 4; break;
    case 2: qt = 7; split = 1; break;
    case 3: qt = 7; par = 1; split = 1; break;
    case 4: qt = 3; break;
    case 5: qt = 6; split = 1; break;
    case 6: qt = 6; par = 1; split = 1; break;
    case 7: qt = 2; break;
    case 8: qt = 1; break;
    default: qt = 0; break;
  }
  int h  = bh & 15;
  int b  = bh >> 4;
  int q0 = qt * 256;
  int tid = threadIdx.x, wave = tid >> 6, lane = tid & 63;
  int quad = lane >> 4, c = lane & 15;
  int tstep = split ? 2 : 1;

  // 64 KB: Qs 32K (reused as per-wave Ps, 8K each) | Ks 2x8K | Vs 2x8K
  __shared__ __attribute__((aligned(16))) __bf16 smem[32768];
  __bf16* Qs = smem;                         // 256*64
  __bf16* Ks = smem + 16384;                 // 2 * 64*64
  __bf16* Vs = smem + 24576;                 // 2 * 64*64 (V^T tiles [d][kv])
  __bf16* Ps = smem + wave * 4096;           // own wave's 64 Q rows (dead after prologue)

  // hoisted per-thread staging addresses (advance additively per tile)
  const __bf16* Kp[2];
  const __bf16* Vp[2];
  int ldst[2];
#pragma unroll
  for (int p = 0; p < 2; ++p) {
    int gg = tid + p * 256;                  // 0..511
    int srow = gg >> 3, sx = ((gg & 7) ^ (srow & 7)) * 8;
    Kp[p] = QKb + ((size_t)(b * S_ + par * 64 + srow)) * 2048 + 1024 + h * 64 + sx;
    Vp[p] = VT + (size_t)bh * (64 * 2048) + (size_t)srow * 2048 + par * 64 + sx;
    ldst[p] = gg * 8;
  }
  const int kstep = tstep * 64 * 2048;
  const int vstep = tstep * 64;

  const __bf16* Qbase = QKb + (size_t)(b * S_ + q0) * 2048 + h * 64;
#pragma unroll
  for (int p = 0; p < 8; ++p) {
    int gg = tid + p * 256;           // 0..2047
    int row = gg >> 3, pch = gg & 7;
    load_lds16(Qbase + (size_t)row * 2048 + (pch ^ (row & 7)) * 8, &Qs[gg * 8]);
  }
#pragma unroll
  for (int p = 0; p < 2; ++p) {       // stage KV tile t=par into buf 0
    load_lds16(Kp[p], &Ks[ldst[p]]);
    load_lds16(Vp[p], &Vs[ldst[p]]);
    Kp[p] += kstep; Vp[p] += vstep;
  }
  __syncthreads();

  bf16x8 qf[4][2];
#pragma unroll
  for (int i = 0; i < 4; ++i)
#pragma unroll
    for (int kk = 0; kk < 2; ++kk)
      qf[i][kk] = *(const bf16x8*)&Qs[swz(wave * 64 + i * 16 + c, kk * 4 + quad)];

  // hoisted fragment offsets (same formula serves kf, vf, pf)
  int offA[4][2], offW[4][4];
#pragma unroll
  for (int j = 0; j < 4; ++j)
#pragma unroll
    for (int kk = 0; kk < 2; ++kk) offA[j][kk] = swz(j * 16 + c, kk * 4 + quad);
#pragma unroll
  for (int i = 0; i < 4; ++i) {
    int q_l = i * 16 + c;
#pragma unroll
    for (int j = 0; j < 4; ++j) {
      int dch8 = j * 2 + (quad >> 1);
      offW[i][j] = q_l * 64 + ((dch8 ^ (q_l & 7)) * 8) + (quad & 1) * 4;
    }
  }

  const __bf16 one_b = (__bf16)1.0f;
  bf16x8 ones = { one_b, one_b, one_b, one_b, one_b, one_b, one_b, one_b };

  f32x4 acc_o[4][4], acc_l[4];
#pragma unroll
  for (int i = 0; i < 4; ++i) {
    acc_l[i] = (f32x4){0.f, 0.f, 0.f, 0.f};
#pragma unroll
    for (int j = 0; j < 4; ++j) acc_o[i][j] = (f32x4){0.f, 0.f, 0.f, 0.f};
  }

  int qwave = q0 + wave * 64;         // this wave's first q row
  int ntiles = qt * 4 + 4;
  int cur = 0;
  for (int t = par; t < ntiles; t += tstep) {
    if (t + tstep < ntiles) {         // prefetch next KV tile (other buffer)
#pragma unroll
      for (int p = 0; p < 2; ++p) {
        load_lds16(Kp[p], &Ks[(cur ^ 1) * 4096 + ldst[p]]);
        load_lds16(Vp[p], &Vs[(cur ^ 1) * 4096 + ldst[p]]);
        Kp[p] += kstep; Vp[p] += vstep;
      }
    }

    int kv0 = t * 64;
    if (kv0 <= qwave + 63) {          // wave has at least one unmasked row
      const __bf16* Kc = Ks + cur * 4096;
      const __bf16* Vc = Vs + cur * 4096;
      bool domask = (kv0 + 63 > qwave);

      bf16x8 kf[4][2];
#pragma unroll
      for (int j = 0; j < 4; ++j)
#pragma unroll
        for (int kk = 0; kk < 2; ++kk)
          kf[j][kk] = *(const bf16x8*)&Kc[offA[j][kk]];

      // per-i: S^T = K Q^T (8 MFMA), exp2(+mask), one b64 P-write per j
#pragma unroll
      for (int i = 0; i < 4; ++i) {
        f32x4 acc_t[4];
#pragma unroll
        for (int j = 0; j < 4; ++j) acc_t[j] = (f32x4){0.f, 0.f, 0.f, 0.f};
#pragma unroll
        for (int j = 0; j < 4; ++j)
#pragma unroll
          for (int kk = 0; kk < 2; ++kk)
            acc_t[j] = mfma16(kf[j][kk], qf[i][kk], acc_t[j]);
        int q_g = qwave + i * 16 + c;              // global q row
#pragma unroll
        for (int j = 0; j < 4; ++j) {
          bf16x4 pk;
#pragma unroll
          for (int r = 0; r < 4; ++r) {
            float p = __builtin_amdgcn_exp2f(acc_t[j][r]);
            if (domask) {
              int kv = kv0 + j * 16 + quad * 4 + r;
              p = (kv > q_g) ? 0.f : p;
            }
            pk[r] = (__bf16)p;
          }
          *(bf16x4*)&Ps[offW[i][j]] = pk;
        }
      }

      // PV + row-sum (ones-MFMA); same-wave LDS ops are in-order
      bf16x8 vf[4][2];
#pragma unroll
      for (int j = 0; j < 4; ++j)
#pragma unroll
        for (int kk = 0; kk < 2; ++kk)
          vf[j][kk] = *(const bf16x8*)&Vc[offA[j][kk]];
#pragma unroll
      for (int i = 0; i < 4; ++i) {
        bf16x8 pf[2];
#pragma unroll
        for (int kk = 0; kk < 2; ++kk)
          pf[kk] = *(const bf16x8*)&Ps[offA[i][kk]];
#pragma unroll
        for (int j = 0; j < 4; ++j)
#pragma unroll
          for (int kk = 0; kk < 2; ++kk)
            acc_o[i][j] = mfma16(pf[kk], vf[j][kk], acc_o[i][j]);
        acc_l[i] = mfma16(pf[0], ones, acc_l[i]);
        acc_l[i] = mfma16(pf[1], ones, acc_l[i]);
      }
    }

    __syncthreads();   // staging for t+tstep complete; buf (cur) free
    cur ^= 1;
  }

  if (!split) {
    __bf16* Obase = O + (size_t)(b * S_ + q0) * 1024 + h * 64;
#pragma unroll
    for (int i = 0; i < 4; ++i)
#pragma unroll
      for (int r = 0; r < 4; ++r) {
        float rl = 1.0f / acc_l[i][r];
        int row = wave * 64 + i * 16 + quad * 4 + r;
#pragma unroll
        for (int j = 0; j < 4; ++j)
          Obase[(size_t)row * 1024 + j * 16 + c] = (__bf16)(acc_o[i][j][r] * rl);
      }
  } else {
    int slot = par * 128 + (7 - qt) * 64 + bh;        // [0,256)
    float* PO = PartO + (size_t)slot * (256 * 64);
    float* PL = PartL + (size_t)slot * 256;
#pragma unroll
    for (int i = 0; i < 4; ++i)
#pragma unroll
      for (int r = 0; r < 4; ++r) {
        int row = wave * 64 + i * 16 + quad * 4 + r;
        if (c == 0) PL[row] = acc_l[i][r];
#pragma unroll
        for (int j = 0; j < 4; ++j)
          PO[row * 64 + j * 16 + c] = acc_o[i][j][r];
      }
  }
}

// merge the kv-parity partials for split q-tiles (qt 7,6): O = (A0+A1)/(l0+l1)
__global__ void merge(const float* __restrict__ PartO, const float* __restrict__ PartL,
                      __bf16* __restrict__ O) {
  int u  = blockIdx.x >> 2;            // 0..127: qtile (qt7: 0..63, qt6: 64..127)
  int r0 = (blockIdx.x & 3) * 64;      // row group within the 256-row q-tile
  int qt = 7 - (u >> 6);
  int bh = u & 63;
  int b = bh >> 4, h = bh & 15;
  int q0 = qt * 256;
  int tid = threadIdx.x;
  const float* A0 = PartO + (size_t)u * (256 * 64) + r0 * 64;
  const float* A1 = PartO + (size_t)(128 + u) * (256 * 64) + r0 * 64;
  const float* L0 = PartL + (size_t)u * 256 + r0;
  const float* L1 = PartL + (size_t)(128 + u) * 256 + r0;
#pragma unroll
  for (int it = 0; it < 4; ++it) {
    int e = it * 1024 + tid * 4;       // elem in 64 rows x 64 d
    int row = e >> 6, d = e & 63;
    f32x4 a0 = *(const f32x4*)&A0[e];
    f32x4 a1 = *(const f32x4*)&A1[e];
    float rl = 1.0f / (L0[row] + L1[row]);
    bf16x4 o;
#pragma unroll
    for (int k = 0; k < 4; ++k) o[k] = (__bf16)((a0[k] + a1[k]) * rl);
    *(bf16x4*)&O[(size_t)(b * S_ + q0 + r0 + row) * 1024 + h * 64 + d] = o;
  }
}

// ---------------- launcher ----------------

extern "C" void kernel_launch(void* const* d_in, const int* in_sizes, int n_in,
                              void* d_out, int out_size, void* d_ws, size_t ws_size,
                              hipStream_t stream) {
  (void)in_sizes; (void)n_in; (void)out_size; (void)ws_size;
  const float* x  = (const float*)d_in[0];
  const float* Wq = (const float*)d_in[1];
  const float* bq = (const float*)d_in[2];
  const float* Wk = (const float*)d_in[3];
  const float* bk = (const float*)d_in[4];
  const float* Wv = (const float*)d_in[5];
  const float* bv = (const float*)d_in[6];
  const float* Wo = (const float*)d_in[7];
  const float* bo = (const float*)d_in[8];

  char* w = (char*)d_ws;
  __bf16* xb   = (__bf16*)(w);                         // 16 MB (dead after gemm1)
  __bf16* Wt   = (__bf16*)(w + (16ull << 20));         //  6 MB (dead after gemm1)
  __bf16* Wot  = (__bf16*)(w + (22ull << 20));         //  2 MB
  float*  bqkv = (float*) (w + (24ull << 20));         // 12 KB
  __bf16* QKb  = (__bf16*)(w + (25ull << 20));         // 32 MB (Q|K, stride 2048)
  __bf16* Ob   = (__bf16*)(w + (57ull << 20));         // 16 MB
  __bf16* VT   = (__bf16*)(w + (73ull << 20));         // 16 MB (total 89 MB)
  // attn partials overlay the dead xb/Wt region (attn runs after gemm1)
  float* PartO = (float*)(w);                          // 16 MB (0..16)
  float* PartL = (float*)(w + (18ull << 20));          // 256 KB (18..18.25)

  prep   <<<9216, 256, 0, stream>>>((const float4*)x, Wq, Wk, Wv, bq, bk, bv, Wo,
                                    xb, Wt, bqkv, Wot);
  gemm_bt<1><<<dim3((MROWS / 128) * (3072 / 128)), 256, 0, stream>>>(xb, Wt, bqkv, (void*)QKb, VT, MROWS, 3072, 1024);
  attn   <<<640, 256, 0, stream>>>(QKb, VT, Ob, PartO, PartL);
  merge  <<<512, 256, 0, stream>>>(PartO, PartL, Ob);
  gemm_bt<0><<<dim3((MROWS / 128) * (1024 / 128)), 256, 0, stream>>>(Ob, Wot, bo, d_out, nullptr, MROWS, 1024, 1024);
}